// Round 1
// baseline (826.481 us; speedup 1.0000x reference)
//
#include <hip/hip_runtime.h>

#define NEG 0.2f

__device__ __forceinline__ float lrelu(float x) { return x >= 0.0f ? x : NEG * x; }

// One block per timestep t. 256 threads.
// LDS layout (floats):
//   sU [100][100] : A_t as stored, i.e. [f][n]  (k-major operand for GEMM-1, k=f, r=n)
//   sV [100][100] : W_h as [f][o]   (k-major operand, c=o); later alphaT [j][i] (k=j, r=i)
//   sH [100][100] : H as [n][o]     (k-major for GEMM-2 with k=j(=n), c=o); later out-transpose [o][i]
//   sas/sad/smx/ssi [100] each
extern "C" __global__ void __launch_bounds__(256, 1)
gat_fused(const float* __restrict__ A, const float* __restrict__ W,
          const float* __restrict__ att_src, const float* __restrict__ att_dst,
          const float* __restrict__ bias, float* __restrict__ out)
{
    extern __shared__ float smem[];
    float* __restrict__ sU  = smem;          // 10000
    float* __restrict__ sV  = smem + 10000;  // 10000
    float* __restrict__ sH  = smem + 20000;  // 10000
    float* __restrict__ sas = smem + 30000;  // 100
    float* __restrict__ sad = smem + 30100;  // 100
    float* __restrict__ smx = smem + 30200;  // 100
    float* __restrict__ ssi = smem + 30300;  // 100

    const int t   = blockIdx.x;
    const int tid = threadIdx.x;
    const float* __restrict__ At = A + (size_t)t * 10000u;

    // ---- load A_t (coalesced, natural layout [f][n]) ----
    for (int idx = tid; idx < 10000; idx += 256) sU[idx] = At[idx];

    // jobs: j = tid + 256*s ; o-quad qc = j%25, r-quad qr = j/25
    // job s=0,1 always valid (tid+256 <= 511 < 625); s=2 valid iff tid < 113.
    float acc[3][16];
#pragma unroll
    for (int s = 0; s < 3; ++s)
#pragma unroll
        for (int e = 0; e < 16; ++e) acc[s][e] = 0.0f;

    for (int h = 0; h < 4; ++h) {
        __syncthreads();  // sV safe to overwrite (prev PV done); also covers initial sU load
        // ---- load W_h transposed -> sV[f][o] (coalesced global read over f) ----
        const float* __restrict__ Wh = W + h * 10000;
        for (int idx = tid; idx < 10000; idx += 256) {
            int o = idx / 100, f = idx - o * 100;
            sV[f * 100 + o] = Wh[idx];
        }
        __syncthreads();

        // ---- GEMM-1: H[n][o] = sum_f sU[f][n] * sV[f][o] ----
#pragma unroll
        for (int s = 0; s < 3; ++s) {
            if (s < 2 || tid < 113) {
                const int j   = tid + 256 * s;
                const int qrr = (j / 25) * 4;
                const int qcc = (j % 25) * 4;
                float hr[16];
#pragma unroll
                for (int e = 0; e < 16; ++e) hr[e] = 0.0f;
                for (int k = 0; k < 100; ++k) {
                    const float4 u = *(const float4*)(sU + k * 100 + qrr);
                    const float4 v = *(const float4*)(sV + k * 100 + qcc);
                    const float uu[4] = {u.x, u.y, u.z, u.w};
                    const float vv[4] = {v.x, v.y, v.z, v.w};
#pragma unroll
                    for (int rr = 0; rr < 4; ++rr)
#pragma unroll
                        for (int cc = 0; cc < 4; ++cc)
                            hr[rr * 4 + cc] = fmaf(uu[rr], vv[cc], hr[rr * 4 + cc]);
                }
#pragma unroll
                for (int rr = 0; rr < 4; ++rr) {
                    float4 w;
                    w.x = hr[rr * 4 + 0]; w.y = hr[rr * 4 + 1];
                    w.z = hr[rr * 4 + 2]; w.w = hr[rr * 4 + 3];
                    *(float4*)(sH + (qrr + rr) * 100 + qcc) = w;
                }
            }
        }
        __syncthreads();

        // ---- attention logits per node: as[n], ad[n] ----
        if (tid < 100) {
            const float* __restrict__ asv = att_src + h * 100;
            const float* __restrict__ adv = att_dst + h * 100;
            float s1 = 0.0f, s2 = 0.0f;
            for (int o = 0; o < 100; ++o) {
                float hv = sH[tid * 100 + o];
                s1 = fmaf(hv, asv[o], s1);
                s2 = fmaf(hv, adv[o], s2);
            }
            sas[tid] = s1;
            sad[tid] = s2;
        }
        __syncthreads();

        // ---- softmax stats per destination i (over sources j) ----
        if (tid < 100) {
            const float adi = sad[tid];
            float m = -1e30f;
            for (int j = 0; j < 100; ++j) m = fmaxf(m, lrelu(adi + sas[j]));
            float sum = 0.0f;
            for (int j = 0; j < 100; ++j) sum += __expf(lrelu(adi + sas[j]) - m);
            smx[tid] = m;
            ssi[tid] = 1.0f / sum;
        }
        __syncthreads();

        // ---- alphaT[j][i] into sV (overwrites W_h) ----
        for (int idx = tid; idx < 10000; idx += 256) {
            int j = idx / 100, i = idx - j * 100;
            float l = lrelu(sad[i] + sas[j]);
            sV[idx] = __expf(l - smx[i]) * ssi[i];
        }
        __syncthreads();

        // ---- GEMM-2 (PV): acc[i][o] += sum_j alphaT[j][i] * sH[j][o] ----
#pragma unroll
        for (int s = 0; s < 3; ++s) {
            if (s < 2 || tid < 113) {
                const int j   = tid + 256 * s;
                const int qrr = (j / 25) * 4;
                const int qcc = (j % 25) * 4;
                for (int k = 0; k < 100; ++k) {
                    const float4 u = *(const float4*)(sV + k * 100 + qrr);
                    const float4 v = *(const float4*)(sH + k * 100 + qcc);
                    const float uu[4] = {u.x, u.y, u.z, u.w};
                    const float vv[4] = {v.x, v.y, v.z, v.w};
#pragma unroll
                    for (int rr = 0; rr < 4; ++rr)
#pragma unroll
                        for (int cc = 0; cc < 4; ++cc)
                            acc[s][rr * 4 + cc] = fmaf(uu[rr], vv[cc], acc[s][rr * 4 + cc]);
                }
            }
        }
    }
    __syncthreads();  // last PV readers of sH done before we overwrite it

    // ---- epilogue: x[i][o] = lrelu(acc/4 + bias[o]); trans[o][i] = x + (o==i) ----
#pragma unroll
    for (int s = 0; s < 3; ++s) {
        if (s < 2 || tid < 113) {
            const int j   = tid + 256 * s;
            const int qrr = (j / 25) * 4;  // i base
            const int qcc = (j % 25) * 4;  // o base
#pragma unroll
            for (int cc = 0; cc < 4; ++cc) {
                const int o = qcc + cc;
                const float b = bias[o];
                float4 w;
                float v0 = lrelu(acc[s][0 * 4 + cc] * 0.25f + b) + ((qrr + 0) == o ? 1.0f : 0.0f);
                float v1 = lrelu(acc[s][1 * 4 + cc] * 0.25f + b) + ((qrr + 1) == o ? 1.0f : 0.0f);
                float v2 = lrelu(acc[s][2 * 4 + cc] * 0.25f + b) + ((qrr + 2) == o ? 1.0f : 0.0f);
                float v3 = lrelu(acc[s][3 * 4 + cc] * 0.25f + b) + ((qrr + 3) == o ? 1.0f : 0.0f);
                w.x = v0; w.y = v1; w.z = v2; w.w = v3;
                *(float4*)(sH + o * 100 + qrr) = w;
            }
        }
    }
    __syncthreads();

    // ---- coalesced store: out[t][o][i] ----
    float* __restrict__ outT = out + (size_t)t * 10000u;
    for (int idx = tid; idx < 10000; idx += 256) outT[idx] = sH[idx];
}

extern "C" void kernel_launch(void* const* d_in, const int* in_sizes, int n_in,
                              void* d_out, int out_size, void* d_ws, size_t ws_size,
                              hipStream_t stream) {
    const float* A      = (const float*)d_in[0];
    const float* W      = (const float*)d_in[1];
    const float* attsrc = (const float*)d_in[2];
    const float* attdst = (const float*)d_in[3];
    const float* bias   = (const float*)d_in[4];
    float* outp = (float*)d_out;

    const int T = in_sizes[0] / 10000;  // 1024
    const int smem_bytes = 30400 * 4;   // 121600 B dynamic LDS (> 64KB needs opt-in)
    hipFuncSetAttribute((const void*)gat_fused,
                        hipFuncAttributeMaxDynamicSharedMemorySize, smem_bytes);
    gat_fused<<<T, 256, smem_bytes, stream>>>(A, W, attsrc, attdst, bias, outp);
}

// Round 2
// 282.691 us; speedup vs baseline: 2.9236x; 2.9236x over previous
//
#include <hip/hip_runtime.h>

typedef __attribute__((ext_vector_type(8))) short bf16x8;
typedef __attribute__((ext_vector_type(4))) float f32x4;
typedef __attribute__((ext_vector_type(4))) unsigned short u16x4;

#define NEG 0.2f
#define LDST 136          // bf16 elems per LDS row (136*2=272B, 16B-aligned, odd*17 banks)

__device__ __forceinline__ float lrelu(float x) { return x >= 0.0f ? x : NEG * x; }

__device__ __forceinline__ unsigned short f2bf(float x) {
    unsigned u = __builtin_bit_cast(unsigned, x);
    u += 0x7FFFu + ((u >> 16) & 1u);          // round-to-nearest-even
    return (unsigned short)(u >> 16);
}
__device__ __forceinline__ float bf2f(unsigned short v) {
    unsigned u = ((unsigned)v) << 16;
    return __builtin_bit_cast(float, u);
}

// One block per t. 256 threads = 4 waves.
// LDS (bytes):
//   X  [112][136] bf16 @ 0      : X[n][f] = A_t^T, zero-padded
//   WA [112][136] bf16 @ 30464  : W_h[o][f] ; later alpha[i][j]
//   HT [112][136] bf16 @ 60928  : H^T[o][j]
//   f32 tails: sas,sad,ssi [112], sp[2][112], sat,sdt [112]
//   sOut f32 [112][104] overlays X+WA at the end.
extern "C" __global__ void __launch_bounds__(256, 1)
gat_mfma(const float* __restrict__ A, const float* __restrict__ W,
         const float* __restrict__ att_src, const float* __restrict__ att_dst,
         const float* __restrict__ bias, float* __restrict__ out)
{
    extern __shared__ char smem[];
    unsigned short* X  = (unsigned short*)(smem);
    unsigned short* WA = (unsigned short*)(smem + 30464);
    unsigned short* HT = (unsigned short*)(smem + 60928);
    float* sas = (float*)(smem + 91392);
    float* sad = sas + 112;
    float* ssi = sad + 112;
    float* sp  = ssi + 112;   // [2][112]
    float* sat = sp  + 224;
    float* sdt = sat + 112;
    float* sOut = (float*)smem;   // [o][104] overlay (X+WA dead by then)

    const int t   = blockIdx.x;
    const int tid = threadIdx.x;
    const int w   = tid >> 6;
    const int l   = tid & 63;
    const int lr  = l & 15;        // row/col-within-tile lane index
    const int lk  = l >> 4;        // k-group
    const float* __restrict__ At = A + (size_t)t * 10000u;

    // ---- zero bf16 buffers (pads must be 0, not NaN) ----
    for (int i = tid; i < 5712; i += 256) ((f32x4*)smem)[i] = (f32x4){0, 0, 0, 0};
    __syncthreads();

    // ---- load + transpose A_t -> X[n][f] (bf16) ----
    for (int idx = tid; idx < 10000; idx += 256) {
        int f = idx / 100, n = idx - f * 100;
        X[n * LDST + f] = f2bf(At[idx]);
    }

    // persistent PV accumulators: wave w owns tile-rows {w, w+4}
    const int nrow = (w < 3) ? 2 : 1;
    const int row0 = w, row1 = w + 4;
    f32x4 acc[2][7];
#pragma unroll
    for (int r = 0; r < 2; ++r)
#pragma unroll
        for (int c = 0; c < 7; ++c) acc[r][c] = (f32x4){0, 0, 0, 0};

    for (int h = 0; h < 4; ++h) {
        __syncthreads();   // prev PV done reading alpha/HT; X ready (h=0)

        // ---- load W_h -> WA[o][f] bf16 (natural layout), att vectors ----
        const float* __restrict__ Wh = W + h * 10000;
        for (int idx = tid; idx < 10000; idx += 256) {
            int o = idx / 100, f = idx - o * 100;
            WA[o * LDST + f] = f2bf(Wh[idx]);
        }
        if (tid < 100)      sat[tid]       = att_src[h * 100 + tid];
        else if (tid < 200) sdt[tid - 100] = att_dst[h * 100 + tid - 100];
        __syncthreads();

        // ---- GEMM-1: H = X * W_h^T ; write HT[o][j] bf16 ----
        {
            f32x4 c1[2][7];
#pragma unroll
            for (int r = 0; r < 2; ++r)
#pragma unroll
                for (int c = 0; c < 7; ++c) c1[r][c] = (f32x4){0, 0, 0, 0};

            for (int ks = 0; ks < 4; ++ks) {
                const int koff = ks * 32 + lk * 8;
                bf16x8 a0 = *(const bf16x8*)(X + (row0 * 16 + lr) * LDST + koff);
                bf16x8 a1 = a0;
                if (nrow > 1) a1 = *(const bf16x8*)(X + (row1 * 16 + lr) * LDST + koff);
#pragma unroll
                for (int tn = 0; tn < 7; ++tn) {
                    bf16x8 b = *(const bf16x8*)(WA + (tn * 16 + lr) * LDST + koff);
                    c1[0][tn] = __builtin_amdgcn_mfma_f32_16x16x32_bf16(a0, b, c1[0][tn], 0, 0, 0);
                    if (nrow > 1)
                        c1[1][tn] = __builtin_amdgcn_mfma_f32_16x16x32_bf16(a1, b, c1[1][tn], 0, 0, 0);
                }
            }
            // C-frag lane holds col o = tn*16+lr, rows j0..j0+3 -> HT[o][j] (4 consec j)
            for (int r = 0; r < nrow; ++r) {
                const int j0 = (r ? row1 : row0) * 16 + 4 * lk;
#pragma unroll
                for (int tn = 0; tn < 7; ++tn) {
                    const int o = tn * 16 + lr;
                    u16x4 p;
                    p.x = f2bf(c1[r][tn].x); p.y = f2bf(c1[r][tn].y);
                    p.z = f2bf(c1[r][tn].z); p.w = f2bf(c1[r][tn].w);
                    *(u16x4*)(HT + o * LDST + j0) = p;
                }
            }
        }
        __syncthreads();   // HT complete

        // ---- logits: a_s[j], a_d[j] = sum_o HT[o][j] * att[o] ----
        if (tid < 100) {
            float s1 = 0.0f, s2 = 0.0f;
            for (int o = 0; o < 100; ++o) {
                float hv = bf2f(HT[o * LDST + tid]);
                s1 = fmaf(hv, sat[o], s1);
                s2 = fmaf(hv, sdt[o], s2);
            }
            sas[tid] = s1; sad[tid] = s2;
        }
        __syncthreads();

        // ---- softmax denom (no max-sub: logits small, f32 safe) ----
        if (tid < 200) {
            const int half = (tid >= 100) ? 1 : 0;
            const int i = tid - half * 100;
            const float adi = sad[i];
            float s = 0.0f;
            const int j0 = half * 50;
            for (int j = j0; j < j0 + 50; ++j) s += __expf(lrelu(adi + sas[j]));
            sp[half * 112 + i] = s;
        }
        __syncthreads();
        if (tid < 100) ssi[tid] = 1.0f / (sp[tid] + sp[112 + tid]);
        __syncthreads();

        // ---- alpha[i][j] bf16 into WA (full cover, 0 in pads) ----
        for (int p2 = tid; p2 < 7616; p2 += 256) {
            const int i = p2 / 68;
            const int jp = (p2 - i * 68) * 2;
            unsigned v = 0;
            if (i < 100) {
                const float adi = sad[i], inv = ssi[i];
                if (jp < 100)     v  = (unsigned)f2bf(__expf(lrelu(adi + sas[jp])) * inv);
                if (jp + 1 < 100) v |= ((unsigned)f2bf(__expf(lrelu(adi + sas[jp + 1])) * inv)) << 16;
            }
            *(unsigned*)(WA + i * LDST + jp) = v;
        }
        __syncthreads();

        // ---- PV: acc += alpha * H  (B-operand = HT) ----
        for (int ks = 0; ks < 4; ++ks) {
            const int koff = ks * 32 + lk * 8;
            bf16x8 a0 = *(const bf16x8*)(WA + (row0 * 16 + lr) * LDST + koff);
            bf16x8 a1 = a0;
            if (nrow > 1) a1 = *(const bf16x8*)(WA + (row1 * 16 + lr) * LDST + koff);
#pragma unroll
            for (int tn = 0; tn < 7; ++tn) {
                bf16x8 b = *(const bf16x8*)(HT + (tn * 16 + lr) * LDST + koff);
                acc[0][tn] = __builtin_amdgcn_mfma_f32_16x16x32_bf16(a0, b, acc[0][tn], 0, 0, 0);
                if (nrow > 1)
                    acc[1][tn] = __builtin_amdgcn_mfma_f32_16x16x32_bf16(a1, b, acc[1][tn], 0, 0, 0);
            }
        }
    }
    __syncthreads();   // all PV done; X/WA dead -> sOut overlay

    // ---- epilogue: sOut[o][i] = lrelu(acc*0.25 + bias[o]) + (i==o) ----
    for (int r = 0; r < nrow; ++r) {
        const int i0 = (r ? row1 : row0) * 16 + 4 * lk;
        if (i0 <= 100) {   // rows i0..i0+3 stay inside the 104-padded row
#pragma unroll
            for (int tn = 0; tn < 7; ++tn) {
                const int o = tn * 16 + lr;
                const float b = bias[o < 100 ? o : 0];
                f32x4 v;
                v.x = lrelu(acc[r][tn].x * 0.25f + b) + ((i0 + 0) == o ? 1.0f : 0.0f);
                v.y = lrelu(acc[r][tn].y * 0.25f + b) + ((i0 + 1) == o ? 1.0f : 0.0f);
                v.z = lrelu(acc[r][tn].z * 0.25f + b) + ((i0 + 2) == o ? 1.0f : 0.0f);
                v.w = lrelu(acc[r][tn].w * 0.25f + b) + ((i0 + 3) == o ? 1.0f : 0.0f);
                *(f32x4*)(sOut + o * 104 + i0) = v;
            }
        }
    }
    __syncthreads();

    // ---- coalesced store out[t][o][i] ----
    float* __restrict__ outT = out + (size_t)t * 10000u;
    for (int idx = tid; idx < 10000; idx += 256) {
        int o = idx / 100, i2 = idx - o * 100;
        outT[idx] = sOut[o * 104 + i2];
    }
}

extern "C" void kernel_launch(void* const* d_in, const int* in_sizes, int n_in,
                              void* d_out, int out_size, void* d_ws, size_t ws_size,
                              hipStream_t stream) {
    const float* A      = (const float*)d_in[0];
    const float* W      = (const float*)d_in[1];
    const float* attsrc = (const float*)d_in[2];
    const float* attdst = (const float*)d_in[3];
    const float* bias   = (const float*)d_in[4];
    float* outp = (float*)d_out;

    const int T = in_sizes[0] / 10000;   // 1024
    const int smem_bytes = 94528;
    hipFuncSetAttribute((const void*)gat_mfma,
                        hipFuncAttributeMaxDynamicSharedMemorySize, smem_bytes);
    gat_mfma<<<T, 256, smem_bytes, stream>>>(A, W, attsrc, attdst, bias, outp);
}